// Round 16
// baseline (616.061 us; speedup 1.0000x reference)
//
#include <hip/hip_runtime.h>
#include <hip/hip_bf16.h>
#include <cstdint>

using bf16 = __hip_bfloat16;
typedef __attribute__((ext_vector_type(8))) short short8;
typedef __attribute__((ext_vector_type(4))) float f32x4;

// ---------------------------------------------------------------- utilities

__device__ __forceinline__ void gld_lds16(const bf16* g, bf16* l) {
  __builtin_amdgcn_global_load_lds(
      (const __attribute__((address_space(1))) void*)g,
      (__attribute__((address_space(3))) void*)l, 16, 0, 0);
}

__device__ __forceinline__ unsigned short f2bf_bits(float f) {
  uint32_t u = __builtin_bit_cast(uint32_t, f);
  uint32_t r = (u + 0x7fffu + ((u >> 16) & 1u)) >> 16;
  return (unsigned short)r;
}

// Bijective XCD-aware swizzle (m204).
__device__ __forceinline__ int xcd_swz(int bid, int nwg) {
  const int q = nwg >> 3, r = nwg & 7;
  const int x = bid & 7, o = bid >> 3;
  return (x < r ? x * (q + 1) : r * (q + 1) + (x - r) * q) + o;
}

// fused cast of the 4 plain [N,K] weights (qkv, proj, fc1, fc2) -> bf16
__global__ void cast4_kernel(const float* __restrict__ s0, bf16* __restrict__ d0,
                             const float* __restrict__ s1, bf16* __restrict__ d1,
                             const float* __restrict__ s2, bf16* __restrict__ d2,
                             const float* __restrict__ s3, bf16* __restrict__ d3)
{
  int i = blockIdx.x * blockDim.x + threadIdx.x;
  const int st = gridDim.x * blockDim.x;
  for (; i < 7077888; i += st) {
    if (i < 1769472)      d0[i] = __float2bfloat16(s0[i]);
    else if (i < 2359296) d1[i - 1769472] = __float2bfloat16(s1[i - 1769472]);
    else if (i < 4718592) d2[i - 2359296] = __float2bfloat16(s2[i - 2359296]);
    else                  d3[i - 4718592] = __float2bfloat16(s3[i - 4718592]);
  }
}

__global__ void zero_b(bf16* __restrict__ p, int n) {
  int i = blockIdx.x * blockDim.x + threadIdx.x;
  if (i < n) p[i] = __float2bfloat16(0.f);
}

// zero only the halo of xp [64,34,34,384]
__global__ __launch_bounds__(256)
void halo_zero(bf16* __restrict__ xp) {
  const int b = blockIdx.x;
  bf16* base = xp + (long)b * 34 * 34 * 384;
  const bf16 z = __float2bfloat16(0.f);
  for (int e = threadIdx.x; e < 132 * 384; e += 256) {
    const int p = e / 384, c = e % 384;
    int iy, ix;
    if (p < 34)       { iy = 0;          ix = p; }
    else if (p < 68)  { iy = 33;         ix = p - 34; }
    else if (p < 100) { iy = p - 68 + 1; ix = 0; }
    else              { iy = p - 100 + 1; ix = 33; }
    base[(iy * 34 + ix) * 384 + c] = z;
  }
}

// conv_w [D, C, 3, 3] -> [D, 3*3, C]  (k' = (ky*3+kx)*384 + c), bf16
__global__ void convw_reorder(const float* __restrict__ w, bf16* __restrict__ o) {
  int i = blockIdx.x * blockDim.x + threadIdx.x;
  if (i >= 768 * 3456) return;
  int n = i / 3456, r = i % 3456;
  int tap = r / 384, c = r % 384;
  o[i] = __float2bfloat16(w[(long)n * 3456 + c * 9 + tap]);
}

// x [64,384,32,32] f32 -> xp [64,34,34,384] bf16 (interior only; halo pre-zeroed)
__global__ __launch_bounds__(256, 4)
void nhwc_kernel(const float* __restrict__ x, bf16* __restrict__ xp) {
  __shared__ bf16 T[384 * 33];            // [c][ix+pad]
  const int biy = blockIdx.x;             // b*32 + iy
  const int b = biy >> 5, iy = biy & 31;
  const int tid = threadIdx.x;
  const int ix = tid & 31, cp = tid >> 5; // cp 0..7
  const long xrow = (long)b * 384 * 1024 + iy * 32 + ix;
#pragma unroll
  for (int t = 0; t < 48; ++t) {
    const int c = t * 8 + cp;
    T[c * 33 + ix] = __float2bfloat16(x[xrow + (long)c * 1024]);
  }
  __syncthreads();
  bf16* dst = xp + (((long)b * 34 + iy + 1) * 34 + 1) * 384;
  for (int e4 = tid; e4 < 3072; e4 += 256) {
    const int e = e4 * 4;
    const int ixr = e / 384, c = e % 384;
    ushort4 v;
    v.x = ((const unsigned short*)T)[(c + 0) * 33 + ixr];
    v.y = ((const unsigned short*)T)[(c + 1) * 33 + ixr];
    v.z = ((const unsigned short*)T)[(c + 2) * 33 + ixr];
    v.w = ((const unsigned short*)T)[(c + 3) * 33 + ixr];
    *(ushort4*)(dst + e) = v;
  }
}

// ---------------------------------------------------------------- GEMM 128x256, 8 waves
// Tile 128(M) x 256(N), BK=64, 8 waves (2M x 4N), 512 threads. Per-WAVE shape
// IDENTICAL to the proven r12 kernel (acc[4][4]=64 VGPR, 8 ds_read_b128, 32
// MFMA per K-step) -- fits the 128-VGPR cap that 512-thread blocks get on
// this toolchain (r6's acc[8][4] needed ~170 and spilled; ~100 here).
// Single-buffered 48 KB LDS (3 blocks/CU), T2 XOR swizzle via pre-swizzled
// source, hoisted LDS read pointers, XCD swizzle. Staging keeps wave-uniform
// base + lane*16B (row=tid>>3, chunk=tid&7 -> linear dest).
// EPI: 0 bf16 out; 1 +bias; 2 +bias+GELU; 3 fp32 residual RMW (row<Mreal).
template <int EPI>
__global__ __launch_bounds__(512)
void gemm_bt(const bf16* __restrict__ A, const bf16* __restrict__ Bw,
             const float* __restrict__ bias, float* __restrict__ outf,
             bf16* __restrict__ outb, int N, int K, int Mreal, int ntn)
{
  __shared__ bf16 As[128 * 64];   // 16 KB
  __shared__ bf16 Bs[256 * 64];   // 32 KB
  const int bid = xcd_swz(blockIdx.x, gridDim.x);
  const int mt = bid / ntn, nt = bid % ntn;
  const int tid = threadIdx.x;
  const int lane = tid & 63, wave = tid >> 6;
  const int wm = wave >> 2, wn = wave & 3;     // 2 x 4
  const int lr = lane & 15, lg = lane >> 4;

  f32x4 acc[4][4];
#pragma unroll
  for (int i = 0; i < 4; ++i)
#pragma unroll
    for (int j = 0; j < 4; ++j) acc[i][j] = (f32x4){0.f, 0.f, 0.f, 0.f};

  const int srow = tid >> 3;                             // 0..63 (j adds 64; &7 invariant)
  const int scol = ((tid & 7) ^ (srow & 7)) * 8;         // pre-swizzled source col
  const bf16* ag = A + ((long)mt * 128 + srow) * K + scol;
  const bf16* bg = Bw + ((long)nt * 256 + srow) * K + scol;

  // hoisted LDS read pointers; fragment index i -> imm offset i*2048.
  const int xs0 = ((lg)     ^ (lr & 7)) * 16;            // ks=0 K-chunk byte off
  const int xs1 = ((lg + 4) ^ (lr & 7)) * 16;            // ks=1
  const char* pa0 = (const char*)As + (wm * 64 + lr) * 128 + xs0;
  const char* pa1 = (const char*)As + (wm * 64 + lr) * 128 + xs1;
  const char* pb0 = (const char*)Bs + (wn * 64 + lr) * 128 + xs0;
  const char* pb1 = (const char*)Bs + (wn * 64 + lr) * 128 + xs1;

  const int nk = K >> 6;
  for (int t = 0; t < nk; ++t) {
    const int k0 = t << 6;
#pragma unroll
    for (int j = 0; j < 2; ++j)
      gld_lds16(ag + (long)(j * 64) * K + k0, &As[(j * 512 + tid) * 8]);
#pragma unroll
    for (int j = 0; j < 4; ++j)
      gld_lds16(bg + (long)(j * 64) * K + k0, &Bs[(j * 512 + tid) * 8]);
    __syncthreads();
#pragma unroll
    for (int ks = 0; ks < 2; ++ks) {
      const char* pa = ks ? pa1 : pa0;
      const char* pb = ks ? pb1 : pb0;
      short8 af[4], bv[4];
#pragma unroll
      for (int i = 0; i < 4; ++i) af[i] = *(const short8*)(pa + i * 2048);
#pragma unroll
      for (int i = 0; i < 4; ++i) bv[i] = *(const short8*)(pb + i * 2048);
#pragma unroll
      for (int i = 0; i < 4; ++i)
#pragma unroll
        for (int j = 0; j < 4; ++j)
          acc[i][j] = __builtin_amdgcn_mfma_f32_16x16x32_bf16(af[i], bv[j], acc[i][j], 0, 0, 0);
    }
    __syncthreads();
  }

  const int rbase = mt * 128 + wm * 64 + lg * 4;
  const int cbase = nt * 256 + wn * 64 + lr;
#pragma unroll
  for (int i = 0; i < 4; ++i) {
#pragma unroll
    for (int j = 0; j < 4; ++j) {
      const int col = cbase + j * 16;
      float bvv = 0.f;
      if constexpr (EPI != 0) bvv = bias[col];
#pragma unroll
      for (int r = 0; r < 4; ++r) {
        const int row = rbase + i * 16 + r;
        const float v = acc[i][j][r];
        if constexpr (EPI == 0) {
          outb[(long)row * N + col] = __float2bfloat16(v);
        } else if constexpr (EPI == 1) {
          outb[(long)row * N + col] = __float2bfloat16(v + bvv);
        } else if constexpr (EPI == 2) {
          const float t = v + bvv;
          outb[(long)row * N + col] =
              __float2bfloat16(0.5f * t * (1.0f + erff(t * 0.70710678118f)));
        } else {
          if (row < Mreal) {
            const long o = (long)row * N + col;
            outf[o] = outf[o] + v + bvv;
          }
        }
      }
    }
  }
}

// ---------------------------------------------------------------- implicit conv GEMM 128x256
__global__ __launch_bounds__(512)
void conv_gemm(const bf16* __restrict__ xp, const bf16* __restrict__ Bw,
               const float* __restrict__ bias, bf16* __restrict__ outb)
{
  __shared__ bf16 As[128 * 64];
  __shared__ bf16 Bs[256 * 64];
  const int bid = xcd_swz(blockIdx.x, gridDim.x);
  const int mt = bid / 3, nt = bid % 3;
  const int tid = threadIdx.x;
  const int lane = tid & 63, wave = tid >> 6;
  const int wm = wave >> 2, wn = wave & 3;
  const int lr = lane & 15, lg = lane >> 4;

  f32x4 acc[4][4];
#pragma unroll
  for (int i = 0; i < 4; ++i)
#pragma unroll
    for (int j = 0; j < 4; ++j) acc[i][j] = (f32x4){0.f, 0.f, 0.f, 0.f};

  const int srow = tid >> 3;
  const int scol = ((tid & 7) ^ (srow & 7)) * 8;
  long abase[2];
#pragma unroll
  for (int j = 0; j < 2; ++j) {
    const int m = mt * 128 + j * 64 + srow;
    const int b = m >> 8, p = m & 255;
    const int gy = p >> 4, gx = p & 15;
    abase[j] = (((long)b * 34 + 2 * gy) * 34 + 2 * gx) * 384 + scol;
  }
  const bf16* bg = Bw + ((long)nt * 256 + srow) * 3456 + scol;

  const int xs0 = ((lg)     ^ (lr & 7)) * 16;
  const int xs1 = ((lg + 4) ^ (lr & 7)) * 16;
  const char* pa0 = (const char*)As + (wm * 64 + lr) * 128 + xs0;
  const char* pa1 = (const char*)As + (wm * 64 + lr) * 128 + xs1;
  const char* pb0 = (const char*)Bs + (wn * 64 + lr) * 128 + xs0;
  const char* pb1 = (const char*)Bs + (wn * 64 + lr) * 128 + xs1;

  for (int t = 0; t < 54; ++t) {
    const int tap = t / 6, kc = (t % 6) * 64;
    const int toff = ((tap / 3) * 34 + (tap % 3)) * 384 + kc;
#pragma unroll
    for (int j = 0; j < 2; ++j)
      gld_lds16(xp + abase[j] + toff, &As[(j * 512 + tid) * 8]);
#pragma unroll
    for (int j = 0; j < 4; ++j)
      gld_lds16(bg + (long)(j * 64) * 3456 + t * 64, &Bs[(j * 512 + tid) * 8]);
    __syncthreads();
#pragma unroll
    for (int ks = 0; ks < 2; ++ks) {
      const char* pa = ks ? pa1 : pa0;
      const char* pb = ks ? pb1 : pb0;
      short8 af[4], bv[4];
#pragma unroll
      for (int i = 0; i < 4; ++i) af[i] = *(const short8*)(pa + i * 2048);
#pragma unroll
      for (int i = 0; i < 4; ++i) bv[i] = *(const short8*)(pb + i * 2048);
#pragma unroll
      for (int i = 0; i < 4; ++i)
#pragma unroll
        for (int j = 0; j < 4; ++j)
          acc[i][j] = __builtin_amdgcn_mfma_f32_16x16x32_bf16(af[i], bv[j], acc[i][j], 0, 0, 0);
    }
    __syncthreads();
  }

  const int rbase = mt * 128 + wm * 64 + lg * 4;
  const int cbase = nt * 256 + wn * 64 + lr;
#pragma unroll
  for (int i = 0; i < 4; ++i) {
#pragma unroll
    for (int j = 0; j < 4; ++j) {
      const int col = cbase + j * 16;
      const float bvv = bias[col];
#pragma unroll
      for (int r = 0; r < 4; ++r) {
        const int row = rbase + i * 16 + r;
        outb[(long)row * 768 + col] = __float2bfloat16(acc[i][j][r] + bvv);
      }
    }
  }
}

// ---------------------------------------------------------------- fused embed + LN1
__global__ __launch_bounds__(256, 4)
void embed_ln_kernel(const bf16* __restrict__ CO, const float* __restrict__ extra,
                     const float* __restrict__ geo, const float* __restrict__ pe_g,
                     const float* __restrict__ pe_b, const float* __restrict__ n1_g,
                     const float* __restrict__ n1_b, float* __restrict__ y,
                     bf16* __restrict__ H)
{
  const int row = blockIdx.x;
  const int tid = threadIdx.x;
  __shared__ float red[2][4];
  const int wave = tid >> 6, lane = tid & 63;
  if (row >= 16448) {
#pragma unroll
    for (int u = 0; u < 3; ++u) H[(long)row * 768 + tid + u * 256] = __float2bfloat16(0.f);
    return;
  }
  const int b = row / 257, t = row % 257;
  float yv[3];
  if (t == 0) {
#pragma unroll
    for (int u = 0; u < 3; ++u) {
      const int d = tid + u * 256;
      yv[u] = extra[d] + geo[d];
    }
  } else {
    const bf16* src = CO + (long)(b * 256 + (t - 1)) * 768;
    float v[3]; float s = 0.f, s2 = 0.f;
#pragma unroll
    for (int u = 0; u < 3; ++u) {
      v[u] = __bfloat162float(src[tid + u * 256]);
      s += v[u]; s2 += v[u] * v[u];
    }
#pragma unroll
    for (int off = 32; off > 0; off >>= 1) { s += __shfl_xor(s, off); s2 += __shfl_xor(s2, off); }
    if (lane == 0) { red[0][wave] = s; red[1][wave] = s2; }
    __syncthreads();
    const float S = red[0][0] + red[0][1] + red[0][2] + red[0][3];
    const float S2 = red[1][0] + red[1][1] + red[1][2] + red[1][3];
    const float mean = S * (1.f / 768.f);
    const float var = S2 * (1.f / 768.f) - mean * mean;
    const float rinv = rsqrtf(var + 1e-5f);
    __syncthreads();   // red[] reused below
#pragma unroll
    for (int u = 0; u < 3; ++u) {
      const int d = tid + u * 256;
      yv[u] = (v[u] - mean) * rinv * pe_g[d] + pe_b[d] + geo[(long)t * 768 + d];
    }
  }
#pragma unroll
  for (int u = 0; u < 3; ++u) y[(long)row * 768 + tid + u * 256] = yv[u];
  float s = 0.f, s2 = 0.f;
#pragma unroll
  for (int u = 0; u < 3; ++u) { s += yv[u]; s2 += yv[u] * yv[u]; }
#pragma unroll
  for (int off = 32; off > 0; off >>= 1) { s += __shfl_xor(s, off); s2 += __shfl_xor(s2, off); }
  if (lane == 0) { red[0][wave] = s; red[1][wave] = s2; }
  __syncthreads();
  const float S = red[0][0] + red[0][1] + red[0][2] + red[0][3];
  const float S2 = red[1][0] + red[1][1] + red[1][2] + red[1][3];
  const float mean = S * (1.f / 768.f);
  const float var = S2 * (1.f / 768.f) - mean * mean;
  const float rinv = rsqrtf(var + 1e-5f);
#pragma unroll
  for (int u = 0; u < 3; ++u) {
    const int d = tid + u * 256;
    H[(long)row * 768 + d] = __float2bfloat16((yv[u] - mean) * rinv * n1_g[d] + n1_b[d]);
  }
}

// ---------------------------------------------------------------- LN -> bf16 (pad rows zeroed)
__global__ __launch_bounds__(256, 4)
void ln_kernel(const float* __restrict__ y, const float* __restrict__ g,
               const float* __restrict__ bta, bf16* __restrict__ H, int Mreal)
{
  const int row = blockIdx.x;
  const int tid = threadIdx.x;
  if (row >= Mreal) {
#pragma unroll
    for (int u = 0; u < 3; ++u) H[(long)row * 768 + tid + u * 256] = __float2bfloat16(0.f);
    return;
  }
  const float* src = y + (long)row * 768;
  float v[3]; float s = 0.f, s2 = 0.f;
#pragma unroll
  for (int u = 0; u < 3; ++u) { v[u] = src[tid + u * 256]; s += v[u]; s2 += v[u] * v[u]; }
#pragma unroll
  for (int off = 32; off > 0; off >>= 1) { s += __shfl_xor(s, off); s2 += __shfl_xor(s2, off); }
  __shared__ float red[2][4];
  const int wave = tid >> 6, lane = tid & 63;
  if (lane == 0) { red[0][wave] = s; red[1][wave] = s2; }
  __syncthreads();
  const float S = red[0][0] + red[0][1] + red[0][2] + red[0][3];
  const float S2 = red[1][0] + red[1][1] + red[1][2] + red[1][3];
  const float mean = S * (1.f / 768.f);
  const float var = S2 * (1.f / 768.f) - mean * mean;
  const float rinv = rsqrtf(var + 1e-5f);
#pragma unroll
  for (int u = 0; u < 3; ++u) {
    const int d = tid + u * 256;
    H[(long)row * 768 + d] = __float2bfloat16((v[u] - mean) * rinv * g[d] + bta[d]);
  }
}

// ---------------------------------------------------------------- rpb transpose: [961,12] -> [12,961]
__global__ void rpbT_kernel(const float* __restrict__ rpb, float* __restrict__ rpbT) {
  int i = blockIdx.x * blockDim.x + threadIdx.x;
  if (i >= 12 * 961) return;
  int h = i / 961, t = i % 961;
  rpbT[i] = rpb[t * 12 + h];
}

// ---------------------------------------------------------------- V transpose:
// QKV V-part [token][d] -> Vt[b][h][d][320] (keys padded with zeros)
__global__ __launch_bounds__(256, 2)
void vtrans_kernel(const bf16* __restrict__ qkv, bf16* __restrict__ vt) {
  __shared__ bf16 Vl[257 * 65];
  const int bh = blockIdx.x;  // b*12+h
  const int b = bh / 12, h = bh % 12;
  const long src = (long)b * 257 * 2304 + 1536 + h * 64;
  for (int e = threadIdx.x; e < 257 * 64; e += 256) {
    const int t = e >> 6, d = e & 63;
    Vl[t * 65 + d] = qkv[src + (long)t * 2304 + d];
  }
  __syncthreads();
  const bf16 z = __float2bfloat16(0.f);
  const long dst = (long)bh * 64 * 320;
  for (int e = threadIdx.x; e < 64 * 320; e += 256) {
    const int d = e / 320, tp = e % 320;
    vt[dst + e] = (tp < 257) ? Vl[tp * 65 + d] : z;
  }
}

// ---------------------------------------------------------------- MFMA flash attention
__global__ __launch_bounds__(256, 2)
void attn_mfma(const bf16* __restrict__ qkv, const bf16* __restrict__ vt,
               const float* __restrict__ rpbT, bf16* __restrict__ O)
{
  __shared__ bf16 Ks[64 * 64];
  __shared__ bf16 Vts[64 * 64];
  __shared__ float rpb_s[961];
  __shared__ bf16 Pl[4][16 * 72];

  const int bid = blockIdx.x;
  const int qb = bid % 5;
  const int bh = bid / 5;
  const int h = bh % 12, b = bh / 12;
  const int tid = threadIdx.x;
  const int lane = tid & 63, w = tid >> 6;
  const int lr = lane & 15, g = lane >> 4;

  for (int t = tid; t < 961; t += 256) rpb_s[t] = rpbT[h * 961 + t];

  const long qkv_bh = (long)b * 257 * 2304 + h * 64;
  const long vt_bh = (long)bh * 64 * 320;

  const int q_tok = qb * 64 + w * 16 + lr;
  const bf16* qp = qkv + qkv_bh + (long)q_tok * 2304;
  short8 qf[2];
  qf[0] = *(const short8*)(qp + g * 8);
  qf[1] = *(const short8*)(qp + 32 + g * 8);

  f32x4 ao[4];
#pragma unroll
  for (int df = 0; df < 4; ++df) ao[df] = (f32x4){0.f, 0.f, 0.f, 0.f};
  float mval = -1e30f, l = 0.f;

  for (int ck = 0; ck < 5; ++ck) {
    const int c0 = ck * 64;
#pragma unroll
    for (int it = 0; it < 2; ++it) {
      const int beta = it * 256 + tid;
      const int row = beta >> 3, cb = beta & 7;
      const int cbs = cb ^ (row & 7);
      gld_lds16(qkv + qkv_bh + (long)(c0 + row) * 2304 + 768 + cbs * 8, &Ks[beta * 8]);
      gld_lds16(vt + vt_bh + (long)row * 320 + c0 + cbs * 8, &Vts[beta * 8]);
    }
    __syncthreads();

    f32x4 st[4];
#pragma unroll
    for (int kf = 0; kf < 4; ++kf) st[kf] = (f32x4){0.f, 0.f, 0.f, 0.f};
#pragma unroll
    for (int ks = 0; ks < 2; ++ks) {
#pragma unroll
      for (int kf = 0; kf < 4; ++kf) {
        const int row = kf * 16 + lr;
        const short8 kfrag = *(const short8*)&Ks[row * 64 + ((ks * 4 + g) ^ (row & 7)) * 8];
        st[kf] = __builtin_amdgcn_mfma_f32_16x16x32_bf16(kfrag, qf[ks], st[kf], 0, 0, 0);
      }
    }

    float p[4][4];
    float t = -1e30f;
#pragma unroll
    for (int kf = 0; kf < 4; ++kf) {
#pragma unroll
      for (int r = 0; r < 4; ++r) {
        const int key = c0 + kf * 16 + g * 4 + r;
        float s;
        if (key < 257) {
          int idx = 0;
          if (q_tok > 0 && key > 0) {
            const int qi = q_tok - 1, kj = key - 1;
            idx = ((qi >> 4) - (kj >> 4) + 15) * 31 + ((qi & 15) - (kj & 15) + 15);
            idx = idx < 0 ? 0 : (idx > 960 ? 960 : idx);
          }
          s = 0.125f * st[kf][r] + rpb_s[idx];
        } else {
          s = -1e30f;
        }
        p[kf][r] = s;
        t = fmaxf(t, s);
      }
    }
    t = fmaxf(t, __shfl_xor(t, 16));
    t = fmaxf(t, __shfl_xor(t, 32));
    const float mnew = fmaxf(mval, t);
    const float corr = __expf(mval - mnew);
    mval = mnew;
    float ps = 0.f;
#pragma unroll
    for (int kf = 0; kf < 4; ++kf)
#pragma unroll
      for (int r = 0; r < 4; ++r) { p[kf][r] = __expf(p[kf][r] - mnew); ps += p[kf][r]; }
    ps += __shfl_xor(ps, 16);
    ps += __shfl_xor(ps, 32);
    l = l * corr + ps;

#pragma unroll
    for (int r = 0; r < 4; ++r) {
      const float cr = __shfl(corr, g * 4 + r);
#pragma unroll
      for (int df = 0; df < 4; ++df) ao[df][r] *= cr;
    }

    bf16* plw = &Pl[w][0];
#pragma unroll
    for (int kf = 0; kf < 4; ++kf) {
      uint2 pw;
      pw.x = ((uint32_t)f2bf_bits(p[kf][1]) << 16) | (uint32_t)f2bf_bits(p[kf][0]);
      pw.y = ((uint32_t)f2bf_bits(p[kf][3]) << 16) | (uint32_t)f2bf_bits(p[kf][2]);
      *(uint2*)&plw[lr * 72 + kf * 16 + g * 4] = pw;
    }

#pragma unroll
    for (int ks = 0; ks < 2; ++ks) {
      const short8 pa = *(const short8*)&plw[lr * 72 + ks * 32 + g * 8];
#pragma unroll
      for (int df = 0; df < 4; ++df) {
        const int row = df * 16 + lr;
        const short8 vfrag = *(const short8*)&Vts[row * 64 + ((ks * 4 + g) ^ (row & 7)) * 8];
        ao[df] = __builtin_amdgcn_mfma_f32_16x16x32_bf16(pa, vfrag, ao[df], 0, 0, 0);
      }
    }
    __syncthreads();
  }

  const float rl = 1.0f / l;
#pragma unroll
  for (int r = 0; r < 4; ++r) {
    const float rr = __shfl(rl, g * 4 + r);
    const int qg = qb * 64 + w * 16 + g * 4 + r;
    if (qg < 257) {
      bf16* op = O + ((long)b * 257 + qg) * 768 + h * 64;
#pragma unroll
      for (int df = 0; df < 4; ++df)
        op[df * 16 + lr] = __float2bfloat16(ao[df][r] * rr);
    }
  }
}

// ---------------------------------------------------------------- launch

extern "C" void kernel_launch(void* const* d_in, const int* in_sizes, int n_in,
                              void* d_out, int out_size, void* d_ws, size_t ws_size,
                              hipStream_t stream) {
  (void)in_sizes; (void)n_in; (void)out_size;
  const float* x      = (const float*)d_in[0];
  const float* geo    = (const float*)d_in[3];
  const float* extra  = (const float*)d_in[4];
  const float* conv_w = (const float*)d_in[5];
  const float* conv_b = (const float*)d_in[6];
  const float* pe_g   = (const float*)d_in[7];
  const float* pe_b   = (const float*)d_in[8];
  const float* n1_g   = (const float*)d_in[9];
  const float* n1_b   = (const float*)d_in[10];
  const float* qkv_w  = (const float*)d_in[11];
  const float* rpb    = (const float*)d_in[12];
  const float* proj_w = (const float*)d_in[13];
  const float* proj_b = (const float*)d_in[14];
  const float* n2_g   = (const float*)d_in[15];
  const float* n2_b   = (const float*)d_in[16];
  const float* fc1_w  = (const float*)d_in[17];
  const float* fc1_b  = (const float*)d_in[18];
  const float* fc2_w  = (const float*)d_in[19];
  const float* fc2_b  = (const float*)d_in[20];
  float* out = (float*)d_out;

  // workspace layout (M padded to 16512 = 129 x 128)
  constexpr size_t SZ_WCONV = 768UL * 3456 * 2;
  constexpr size_t SZ_WQKV  = 2304UL * 768 * 2;
  constexpr size_t SZ_WPROJ = 768UL * 768 * 2;
  constexpr size_t SZ_WFC1  = 3072UL * 768 * 2;
  constexpr size_t SZ_WFC2  = 768UL * 3072 * 2;
  constexpr size_t SZ_H     = 16512UL * 768 * 2;
  constexpr size_t SZ_A     = 16384UL * 3456 * 2;
  constexpr size_t SZ_B     = 16512UL * 768 * 2;
  constexpr size_t TOTAL = SZ_WCONV + SZ_WQKV + SZ_WPROJ + SZ_WFC1 + SZ_WFC2 + SZ_H + SZ_A + SZ_B;
  if (ws_size < TOTAL) return;

  char* ws = (char*)d_ws;
  bf16* Wconv = (bf16*)ws;                    ws += SZ_WCONV;
  bf16* Wqkv  = (bf16*)ws;                    ws += SZ_WQKV;
  bf16* Wproj = (bf16*)ws;                    ws += SZ_WPROJ;
  bf16* Wfc1  = (bf16*)ws;                    ws += SZ_WFC1;
  bf16* Wfc2  = (bf16*)ws;                    ws += SZ_WFC2;
  bf16* Hb    = (bf16*)ws;                    ws += SZ_H;
  char* regA  = ws;                           ws += SZ_A;
  char* regB  = ws;
  bf16* XP   = (bf16*)regA;     // phase: conv — NHWC halo-padded input (56.8 MB)
  bf16* QKV  = (bf16*)regA;     // phase: attention
  bf16* MLPH = (bf16*)regA;     // phase: mlp
  constexpr size_t SZ_QKV = 16512UL * 2304 * 2;       // 76.1 MB
  bf16* Vt   = (bf16*)(regA + SZ_QKV);                // 31.5 MB (fits SZ_A slack)
  bf16* CO   = (bf16*)regB;     // conv out (bf16, +bias)
  bf16* Oat  = (bf16*)regB;     // attention out
  float* rpbTp = (float*)Hb;    // 46KB, Hb is free during attention

  // 1) weight casts (fused) + NHWC transpose (halo-only zero)
  convw_reorder<<<10368, 256, 0, stream>>>(conv_w, Wconv);
  cast4_kernel<<<2048, 256, 0, stream>>>(qkv_w, Wqkv, proj_w, Wproj, fc1_w, Wfc1, fc2_w, Wfc2);
  halo_zero<<<64, 256, 0, stream>>>(XP);
  nhwc_kernel<<<2048, 256, 0, stream>>>(x, XP);
  // 2) implicit conv GEMM (+bias) -> CO  (128 m-tiles x 3 n-tiles of 256)
  conv_gemm<<<128 * 3, 512, 0, stream>>>(XP, Wconv, conv_b, CO);
  // 3) fused embed + LN1 -> y (d_out) and Hb
  embed_ln_kernel<<<16512, 256, 0, stream>>>(CO, extra, geo, pe_g, pe_b, n1_g, n1_b, out, Hb);
  // 4) QKV GEMM (129 x 9)
  gemm_bt<0><<<129 * 9, 512, 0, stream>>>(Hb, Wqkv, nullptr, nullptr, QKV, 2304, 768, 16448, 9);
  // 5) attention prep: rpb transpose, V transpose, zero Oat pad rows
  rpbT_kernel<<<46, 256, 0, stream>>>(rpb, rpbTp);
  vtrans_kernel<<<768, 256, 0, stream>>>(QKV, Vt);
  zero_b<<<192, 256, 0, stream>>>(Oat + 16448L * 768, 49152);
  // 6) MFMA flash attention -> Oat
  attn_mfma<<<3840, 256, 0, stream>>>(QKV, Vt, rpbTp, Oat);
  // 7) proj GEMM + bias + residual (in-place on d_out) (129 x 3)
  gemm_bt<3><<<129 * 3, 512, 0, stream>>>(Oat, Wproj, proj_b, out, nullptr, 768, 768, 16448, 3);
  // 8) LN2 -> Hb ; FC1 (+bias+GELU) -> MLPH (129 x 12) ; FC2 + residual (129 x 3)
  ln_kernel<<<16512, 256, 0, stream>>>(out, n2_g, n2_b, Hb, 16448);
  gemm_bt<2><<<129 * 12, 512, 0, stream>>>(Hb, Wfc1, fc1_b, nullptr, MLPH, 3072, 768, 16448, 12);
  gemm_bt<3><<<129 * 3, 512, 0, stream>>>(MLPH, Wfc2, fc2_b, out, nullptr, 768, 3072, 16448, 3);
}

// Round 17
// 607.028 us; speedup vs baseline: 1.0149x; 1.0149x over previous
//
#include <hip/hip_runtime.h>
#include <hip/hip_bf16.h>
#include <cstdint>

using bf16 = __hip_bfloat16;
typedef __attribute__((ext_vector_type(8))) short short8;
typedef __attribute__((ext_vector_type(4))) float f32x4;

// ---------------------------------------------------------------- utilities

__device__ __forceinline__ void gld_lds16(const bf16* g, bf16* l) {
  __builtin_amdgcn_global_load_lds(
      (const __attribute__((address_space(1))) void*)g,
      (__attribute__((address_space(3))) void*)l, 16, 0, 0);
}

__device__ __forceinline__ unsigned short f2bf_bits(float f) {
  uint32_t u = __builtin_bit_cast(uint32_t, f);
  uint32_t r = (u + 0x7fffu + ((u >> 16) & 1u)) >> 16;
  return (unsigned short)r;
}

// Bijective XCD-aware swizzle (m204).
__device__ __forceinline__ int xcd_swz(int bid, int nwg) {
  const int q = nwg >> 3, r = nwg & 7;
  const int x = bid & 7, o = bid >> 3;
  return (x < r ? x * (q + 1) : r * (q + 1) + (x - r) * q) + o;
}

// fused cast of the 4 plain [N,K] weights (qkv, proj, fc1, fc2) -> bf16
__global__ void cast4_kernel(const float* __restrict__ s0, bf16* __restrict__ d0,
                             const float* __restrict__ s1, bf16* __restrict__ d1,
                             const float* __restrict__ s2, bf16* __restrict__ d2,
                             const float* __restrict__ s3, bf16* __restrict__ d3)
{
  int i = blockIdx.x * blockDim.x + threadIdx.x;
  const int st = gridDim.x * blockDim.x;
  for (; i < 7077888; i += st) {
    if (i < 1769472)      d0[i] = __float2bfloat16(s0[i]);
    else if (i < 2359296) d1[i - 1769472] = __float2bfloat16(s1[i - 1769472]);
    else if (i < 4718592) d2[i - 2359296] = __float2bfloat16(s2[i - 2359296]);
    else                  d3[i - 4718592] = __float2bfloat16(s3[i - 4718592]);
  }
}

__global__ void zero_b(bf16* __restrict__ p, int n) {
  int i = blockIdx.x * blockDim.x + threadIdx.x;
  if (i < n) p[i] = __float2bfloat16(0.f);
}

// zero only the halo of xp [64,34,34,384]
__global__ __launch_bounds__(256)
void halo_zero(bf16* __restrict__ xp) {
  const int b = blockIdx.x;
  bf16* base = xp + (long)b * 34 * 34 * 384;
  const bf16 z = __float2bfloat16(0.f);
  for (int e = threadIdx.x; e < 132 * 384; e += 256) {
    const int p = e / 384, c = e % 384;
    int iy, ix;
    if (p < 34)       { iy = 0;          ix = p; }
    else if (p < 68)  { iy = 33;         ix = p - 34; }
    else if (p < 100) { iy = p - 68 + 1; ix = 0; }
    else              { iy = p - 100 + 1; ix = 33; }
    base[(iy * 34 + ix) * 384 + c] = z;
  }
}

// conv_w [D, C, 3, 3] -> [D, 3*3, C]  (k' = (ky*3+kx)*384 + c), bf16
__global__ void convw_reorder(const float* __restrict__ w, bf16* __restrict__ o) {
  int i = blockIdx.x * blockDim.x + threadIdx.x;
  if (i >= 768 * 3456) return;
  int n = i / 3456, r = i % 3456;
  int tap = r / 384, c = r % 384;
  o[i] = __float2bfloat16(w[(long)n * 3456 + c * 9 + tap]);
}

// x [64,384,32,32] f32 -> xp [64,34,34,384] bf16 (interior only; halo pre-zeroed)
__global__ __launch_bounds__(256, 4)
void nhwc_kernel(const float* __restrict__ x, bf16* __restrict__ xp) {
  __shared__ bf16 T[384 * 33];            // [c][ix+pad]
  const int biy = blockIdx.x;             // b*32 + iy
  const int b = biy >> 5, iy = biy & 31;
  const int tid = threadIdx.x;
  const int ix = tid & 31, cp = tid >> 5; // cp 0..7
  const long xrow = (long)b * 384 * 1024 + iy * 32 + ix;
#pragma unroll
  for (int t = 0; t < 48; ++t) {
    const int c = t * 8 + cp;
    T[c * 33 + ix] = __float2bfloat16(x[xrow + (long)c * 1024]);
  }
  __syncthreads();
  bf16* dst = xp + (((long)b * 34 + iy + 1) * 34 + 1) * 384;
  for (int e4 = tid; e4 < 3072; e4 += 256) {
    const int e = e4 * 4;
    const int ixr = e / 384, c = e % 384;
    ushort4 v;
    v.x = ((const unsigned short*)T)[(c + 0) * 33 + ixr];
    v.y = ((const unsigned short*)T)[(c + 1) * 33 + ixr];
    v.z = ((const unsigned short*)T)[(c + 2) * 33 + ixr];
    v.w = ((const unsigned short*)T)[(c + 3) * 33 + ixr];
    *(ushort4*)(dst + e) = v;
  }
}

// ---------------------------------------------------------------- GEMM (round-12 proven; UNCHANGED)
// 128x128 tile, BK=64, 4 waves 2x2, SINGLE-buffered 32 KB LDS, T2 XOR swizzle
// via pre-swizzled source, hoisted LDS read pointers, XCD swizzle. 256
// threads/block REQUIRED. Four structural variants (64KB dbuf r11, LDS-bounce
// epilogue r13, BK=32 dbuf r14, 128x256 8-wave r16) all regressed -- this is
// the measured local optimum of the family (615 us total, FC1 112.6 us).
// EPI: 0 bf16 out; 1 +bias; 2 +bias+GELU; 3 fp32 residual RMW (row<Mreal).
template <int EPI>
__global__ __launch_bounds__(256, 2)
void gemm_bt(const bf16* __restrict__ A, const bf16* __restrict__ Bw,
             const float* __restrict__ bias, float* __restrict__ outf,
             bf16* __restrict__ outb, int N, int K, int Mreal, int ntn)
{
  __shared__ bf16 As[128 * 64];
  __shared__ bf16 Bs[128 * 64];
  const int bid = xcd_swz(blockIdx.x, gridDim.x);
  const int mt = bid / ntn, nt = bid % ntn;
  const int tid = threadIdx.x;
  const int lane = tid & 63, wave = tid >> 6;
  const int wm = wave >> 1, wn = wave & 1;
  const int lr = lane & 15, lg = lane >> 4;

  f32x4 acc[4][4];
#pragma unroll
  for (int i = 0; i < 4; ++i)
#pragma unroll
    for (int j = 0; j < 4; ++j) acc[i][j] = (f32x4){0.f, 0.f, 0.f, 0.f};

  const int arow = tid >> 3;                               // 0..31
  const int scol = (((tid & 7) ^ (arow & 7))) * 8;         // pre-swizzled source col
  const bf16* ag = A + ((long)mt * 128 + arow) * K + scol;
  const bf16* bg = Bw + ((long)nt * 128 + arow) * K + scol;

  const int xs0 = ((lg)     ^ (lr & 7)) * 16;              // ks=0 K-chunk byte off
  const int xs1 = ((lg + 4) ^ (lr & 7)) * 16;              // ks=1
  const char* pa0 = (const char*)(&As[0]) + (wm * 64 + lr) * 128 + xs0;
  const char* pa1 = (const char*)(&As[0]) + (wm * 64 + lr) * 128 + xs1;
  const char* pb0 = (const char*)(&Bs[0]) + (wn * 64 + lr) * 128 + xs0;
  const char* pb1 = (const char*)(&Bs[0]) + (wn * 64 + lr) * 128 + xs1;

  const int nk = K >> 6;
  for (int t = 0; t < nk; ++t) {
    const int k0 = t << 6;
#pragma unroll
    for (int j = 0; j < 4; ++j) {
      gld_lds16(ag + (long)(j * 32) * K + k0, &As[(j * 256 + tid) * 8]);
      gld_lds16(bg + (long)(j * 32) * K + k0, &Bs[(j * 256 + tid) * 8]);
    }
    __syncthreads();
#pragma unroll
    for (int ks = 0; ks < 2; ++ks) {
      const char* pa = ks ? pa1 : pa0;
      const char* pb = ks ? pb1 : pb0;
      short8 af[4], bv[4];
#pragma unroll
      for (int i = 0; i < 4; ++i) af[i] = *(const short8*)(pa + i * 2048);
#pragma unroll
      for (int i = 0; i < 4; ++i) bv[i] = *(const short8*)(pb + i * 2048);
#pragma unroll
      for (int i = 0; i < 4; ++i)
#pragma unroll
        for (int j = 0; j < 4; ++j)
          acc[i][j] = __builtin_amdgcn_mfma_f32_16x16x32_bf16(af[i], bv[j], acc[i][j], 0, 0, 0);
    }
    __syncthreads();
  }

  const int rbase = mt * 128 + wm * 64 + (lane >> 4) * 4;
  const int cbase = nt * 128 + wn * 64 + lr;
#pragma unroll
  for (int i = 0; i < 4; ++i) {
#pragma unroll
    for (int j = 0; j < 4; ++j) {
      const int col = cbase + j * 16;
      float bvv = 0.f;
      if constexpr (EPI != 0) bvv = bias[col];
#pragma unroll
      for (int r = 0; r < 4; ++r) {
        const int row = rbase + i * 16 + r;
        const float v = acc[i][j][r];
        if constexpr (EPI == 0) {
          outb[(long)row * N + col] = __float2bfloat16(v);
        } else if constexpr (EPI == 1) {
          outb[(long)row * N + col] = __float2bfloat16(v + bvv);
        } else if constexpr (EPI == 2) {
          const float t = v + bvv;
          outb[(long)row * N + col] =
              __float2bfloat16(0.5f * t * (1.0f + erff(t * 0.70710678118f)));
        } else {
          if (row < Mreal) {
            const long o = (long)row * N + col;
            outf[o] = outf[o] + v + bvv;
          }
        }
      }
    }
  }
}

// ---------------------------------------------------------------- implicit conv GEMM (round-12)
__global__ __launch_bounds__(256, 2)
void conv_gemm(const bf16* __restrict__ xp, const bf16* __restrict__ Bw,
               const float* __restrict__ bias, bf16* __restrict__ outb)
{
  __shared__ bf16 As[128 * 64];
  __shared__ bf16 Bs[128 * 64];
  const int bid = xcd_swz(blockIdx.x, gridDim.x);
  const int mt = bid / 6, nt = bid % 6;
  const int tid = threadIdx.x;
  const int lane = tid & 63, wave = tid >> 6;
  const int wm = wave >> 1, wn = wave & 1;
  const int lr = lane & 15, lg = lane >> 4;

  f32x4 acc[4][4];
#pragma unroll
  for (int i = 0; i < 4; ++i)
#pragma unroll
    for (int j = 0; j < 4; ++j) acc[i][j] = (f32x4){0.f, 0.f, 0.f, 0.f};

  const int arow = tid >> 3;
  const int scol = (((tid & 7) ^ (arow & 7))) * 8;
  long abase[4];
#pragma unroll
  for (int j = 0; j < 4; ++j) {
    const int m = mt * 128 + j * 32 + arow;
    const int b = m >> 8, p = m & 255;
    const int gy = p >> 4, gx = p & 15;
    abase[j] = (((long)b * 34 + 2 * gy) * 34 + 2 * gx) * 384 + scol;
  }
  const bf16* bg = Bw + ((long)nt * 128 + arow) * 3456 + scol;

  const int xs0 = ((lg)     ^ (lr & 7)) * 16;
  const int xs1 = ((lg + 4) ^ (lr & 7)) * 16;
  const char* pa0 = (const char*)(&As[0]) + (wm * 64 + lr) * 128 + xs0;
  const char* pa1 = (const char*)(&As[0]) + (wm * 64 + lr) * 128 + xs1;
  const char* pb0 = (const char*)(&Bs[0]) + (wn * 64 + lr) * 128 + xs0;
  const char* pb1 = (const char*)(&Bs[0]) + (wn * 64 + lr) * 128 + xs1;

  for (int t = 0; t < 54; ++t) {
    const int tap = t / 6, kc = (t % 6) * 64;
    const int toff = ((tap / 3) * 34 + (tap % 3)) * 384 + kc;
#pragma unroll
    for (int j = 0; j < 4; ++j) {
      gld_lds16(xp + abase[j] + toff, &As[(j * 256 + tid) * 8]);
      gld_lds16(bg + (long)(j * 32) * 3456 + t * 64, &Bs[(j * 256 + tid) * 8]);
    }
    __syncthreads();
#pragma unroll
    for (int ks = 0; ks < 2; ++ks) {
      const char* pa = ks ? pa1 : pa0;
      const char* pb = ks ? pb1 : pb0;
      short8 af[4], bv[4];
#pragma unroll
      for (int i = 0; i < 4; ++i) af[i] = *(const short8*)(pa + i * 2048);
#pragma unroll
      for (int i = 0; i < 4; ++i) bv[i] = *(const short8*)(pb + i * 2048);
#pragma unroll
      for (int i = 0; i < 4; ++i)
#pragma unroll
        for (int j = 0; j < 4; ++j)
          acc[i][j] = __builtin_amdgcn_mfma_f32_16x16x32_bf16(af[i], bv[j], acc[i][j], 0, 0, 0);
    }
    __syncthreads();
  }

  const int rbase = mt * 128 + wm * 64 + (lane >> 4) * 4;
  const int cbase = nt * 128 + wn * 64 + lr;
#pragma unroll
  for (int i = 0; i < 4; ++i) {
#pragma unroll
    for (int j = 0; j < 4; ++j) {
      const int col = cbase + j * 16;
      const float bvv = bias[col];
#pragma unroll
      for (int r = 0; r < 4; ++r) {
        const int row = rbase + i * 16 + r;
        outb[(long)row * 768 + col] = __float2bfloat16(acc[i][j][r] + bvv);
      }
    }
  }
}

// ---------------------------------------------------------------- fused embed + LN1
__global__ __launch_bounds__(256, 4)
void embed_ln_kernel(const bf16* __restrict__ CO, const float* __restrict__ extra,
                     const float* __restrict__ geo, const float* __restrict__ pe_g,
                     const float* __restrict__ pe_b, const float* __restrict__ n1_g,
                     const float* __restrict__ n1_b, float* __restrict__ y,
                     bf16* __restrict__ H)
{
  const int row = blockIdx.x;
  const int tid = threadIdx.x;
  __shared__ float red[2][4];
  const int wave = tid >> 6, lane = tid & 63;
  if (row >= 16448) {
#pragma unroll
    for (int u = 0; u < 3; ++u) H[(long)row * 768 + tid + u * 256] = __float2bfloat16(0.f);
    return;
  }
  const int b = row / 257, t = row % 257;
  float yv[3];
  if (t == 0) {
#pragma unroll
    for (int u = 0; u < 3; ++u) {
      const int d = tid + u * 256;
      yv[u] = extra[d] + geo[d];
    }
  } else {
    const bf16* src = CO + (long)(b * 256 + (t - 1)) * 768;
    float v[3]; float s = 0.f, s2 = 0.f;
#pragma unroll
    for (int u = 0; u < 3; ++u) {
      v[u] = __bfloat162float(src[tid + u * 256]);
      s += v[u]; s2 += v[u] * v[u];
    }
#pragma unroll
    for (int off = 32; off > 0; off >>= 1) { s += __shfl_xor(s, off); s2 += __shfl_xor(s2, off); }
    if (lane == 0) { red[0][wave] = s; red[1][wave] = s2; }
    __syncthreads();
    const float S = red[0][0] + red[0][1] + red[0][2] + red[0][3];
    const float S2 = red[1][0] + red[1][1] + red[1][2] + red[1][3];
    const float mean = S * (1.f / 768.f);
    const float var = S2 * (1.f / 768.f) - mean * mean;
    const float rinv = rsqrtf(var + 1e-5f);
    __syncthreads();   // red[] reused below
#pragma unroll
    for (int u = 0; u < 3; ++u) {
      const int d = tid + u * 256;
      yv[u] = (v[u] - mean) * rinv * pe_g[d] + pe_b[d] + geo[(long)t * 768 + d];
    }
  }
#pragma unroll
  for (int u = 0; u < 3; ++u) y[(long)row * 768 + tid + u * 256] = yv[u];
  float s = 0.f, s2 = 0.f;
#pragma unroll
  for (int u = 0; u < 3; ++u) { s += yv[u]; s2 += yv[u] * yv[u]; }
#pragma unroll
  for (int off = 32; off > 0; off >>= 1) { s += __shfl_xor(s, off); s2 += __shfl_xor(s2, off); }
  if (lane == 0) { red[0][wave] = s; red[1][wave] = s2; }
  __syncthreads();
  const float S = red[0][0] + red[0][1] + red[0][2] + red[0][3];
  const float S2 = red[1][0] + red[1][1] + red[1][2] + red[1][3];
  const float mean = S * (1.f / 768.f);
  const float var = S2 * (1.f / 768.f) - mean * mean;
  const float rinv = rsqrtf(var + 1e-5f);
#pragma unroll
  for (int u = 0; u < 3; ++u) {
    const int d = tid + u * 256;
    H[(long)row * 768 + d] = __float2bfloat16((yv[u] - mean) * rinv * n1_g[d] + n1_b[d]);
  }
}

// ---------------------------------------------------------------- LN -> bf16 (pad rows zeroed)
__global__ __launch_bounds__(256, 4)
void ln_kernel(const float* __restrict__ y, const float* __restrict__ g,
               const float* __restrict__ bta, bf16* __restrict__ H, int Mreal)
{
  const int row = blockIdx.x;
  const int tid = threadIdx.x;
  if (row >= Mreal) {
#pragma unroll
    for (int u = 0; u < 3; ++u) H[(long)row * 768 + tid + u * 256] = __float2bfloat16(0.f);
    return;
  }
  const float* src = y + (long)row * 768;
  float v[3]; float s = 0.f, s2 = 0.f;
#pragma unroll
  for (int u = 0; u < 3; ++u) { v[u] = src[tid + u * 256]; s += v[u]; s2 += v[u] * v[u]; }
#pragma unroll
  for (int off = 32; off > 0; off >>= 1) { s += __shfl_xor(s, off); s2 += __shfl_xor(s2, off); }
  __shared__ float red[2][4];
  const int wave = tid >> 6, lane = tid & 63;
  if (lane == 0) { red[0][wave] = s; red[1][wave] = s2; }
  __syncthreads();
  const float S = red[0][0] + red[0][1] + red[0][2] + red[0][3];
  const float S2 = red[1][0] + red[1][1] + red[1][2] + red[1][3];
  const float mean = S * (1.f / 768.f);
  const float var = S2 * (1.f / 768.f) - mean * mean;
  const float rinv = rsqrtf(var + 1e-5f);
#pragma unroll
  for (int u = 0; u < 3; ++u) {
    const int d = tid + u * 256;
    H[(long)row * 768 + d] = __float2bfloat16((v[u] - mean) * rinv * g[d] + bta[d]);
  }
}

// ---------------------------------------------------------------- rpb transpose: [961,12] -> [12,961]
__global__ void rpbT_kernel(const float* __restrict__ rpb, float* __restrict__ rpbT) {
  int i = blockIdx.x * blockDim.x + threadIdx.x;
  if (i >= 12 * 961) return;
  int h = i / 961, t = i % 961;
  rpbT[i] = rpb[t * 12 + h];
}

// ---------------------------------------------------------------- V transpose:
// QKV V-part [token][d] -> Vt[b][h][d][320] (keys padded with zeros)
__global__ __launch_bounds__(256, 2)
void vtrans_kernel(const bf16* __restrict__ qkv, bf16* __restrict__ vt) {
  __shared__ bf16 Vl[257 * 65];
  const int bh = blockIdx.x;  // b*12+h
  const int b = bh / 12, h = bh % 12;
  const long src = (long)b * 257 * 2304 + 1536 + h * 64;
  for (int e = threadIdx.x; e < 257 * 64; e += 256) {
    const int t = e >> 6, d = e & 63;
    Vl[t * 65 + d] = qkv[src + (long)t * 2304 + d];
  }
  __syncthreads();
  const bf16 z = __float2bfloat16(0.f);
  const long dst = (long)bh * 64 * 320;
  for (int e = threadIdx.x; e < 64 * 320; e += 256) {
    const int d = e / 320, tp = e % 320;
    vt[dst + e] = (tp < 257) ? Vl[tp * 65 + d] : z;
  }
}

// ---------------------------------------------------------------- MFMA flash attention
// r17: T5 s_setprio(1) wrapped around both MFMA clusters (m191 regime:
// many independent blocks per CU -> scheduler can prefer MFMA-entering waves).
__global__ __launch_bounds__(256, 2)
void attn_mfma(const bf16* __restrict__ qkv, const bf16* __restrict__ vt,
               const float* __restrict__ rpbT, bf16* __restrict__ O)
{
  __shared__ bf16 Ks[64 * 64];
  __shared__ bf16 Vts[64 * 64];
  __shared__ float rpb_s[961];
  __shared__ bf16 Pl[4][16 * 72];

  const int bid = blockIdx.x;
  const int qb = bid % 5;
  const int bh = bid / 5;
  const int h = bh % 12, b = bh / 12;
  const int tid = threadIdx.x;
  const int lane = tid & 63, w = tid >> 6;
  const int lr = lane & 15, g = lane >> 4;

  for (int t = tid; t < 961; t += 256) rpb_s[t] = rpbT[h * 961 + t];

  const long qkv_bh = (long)b * 257 * 2304 + h * 64;
  const long vt_bh = (long)bh * 64 * 320;

  const int q_tok = qb * 64 + w * 16 + lr;
  const bf16* qp = qkv + qkv_bh + (long)q_tok * 2304;
  short8 qf[2];
  qf[0] = *(const short8*)(qp + g * 8);
  qf[1] = *(const short8*)(qp + 32 + g * 8);

  f32x4 ao[4];
#pragma unroll
  for (int df = 0; df < 4; ++df) ao[df] = (f32x4){0.f, 0.f, 0.f, 0.f};
  float mval = -1e30f, l = 0.f;

  for (int ck = 0; ck < 5; ++ck) {
    const int c0 = ck * 64;
#pragma unroll
    for (int it = 0; it < 2; ++it) {
      const int beta = it * 256 + tid;
      const int row = beta >> 3, cb = beta & 7;
      const int cbs = cb ^ (row & 7);
      gld_lds16(qkv + qkv_bh + (long)(c0 + row) * 2304 + 768 + cbs * 8, &Ks[beta * 8]);
      gld_lds16(vt + vt_bh + (long)row * 320 + c0 + cbs * 8, &Vts[beta * 8]);
    }
    __syncthreads();

    f32x4 st[4];
#pragma unroll
    for (int kf = 0; kf < 4; ++kf) st[kf] = (f32x4){0.f, 0.f, 0.f, 0.f};
    __builtin_amdgcn_s_setprio(1);
#pragma unroll
    for (int ks = 0; ks < 2; ++ks) {
#pragma unroll
      for (int kf = 0; kf < 4; ++kf) {
        const int row = kf * 16 + lr;
        const short8 kfrag = *(const short8*)&Ks[row * 64 + ((ks * 4 + g) ^ (row & 7)) * 8];
        st[kf] = __builtin_amdgcn_mfma_f32_16x16x32_bf16(kfrag, qf[ks], st[kf], 0, 0, 0);
      }
    }
    __builtin_amdgcn_s_setprio(0);

    float p[4][4];
    float t = -1e30f;
#pragma unroll
    for (int kf = 0; kf < 4; ++kf) {
#pragma unroll
      for (int r = 0; r < 4; ++r) {
        const int key = c0 + kf * 16 + g * 4 + r;
        float s;
        if (key < 257) {
          int idx = 0;
          if (q_tok > 0 && key > 0) {
            const int qi = q_tok - 1, kj = key - 1;
            idx = ((qi >> 4) - (kj >> 4) + 15) * 31 + ((qi & 15) - (kj & 15) + 15);
            idx = idx < 0 ? 0 : (idx > 960 ? 960 : idx);
          }
          s = 0.125f * st[kf][r] + rpb_s[idx];
        } else {
          s = -1e30f;
        }
        p[kf][r] = s;
        t = fmaxf(t, s);
      }
    }
    t = fmaxf(t, __shfl_xor(t, 16));
    t = fmaxf(t, __shfl_xor(t, 32));
    const float mnew = fmaxf(mval, t);
    const float corr = __expf(mval - mnew);
    mval = mnew;
    float ps = 0.f;
#pragma unroll
    for (int kf = 0; kf < 4; ++kf)
#pragma unroll
      for (int r = 0; r < 4; ++r) { p[kf][r] = __expf(p[kf][r] - mnew); ps += p[kf][r]; }
    ps += __shfl_xor(ps, 16);
    ps += __shfl_xor(ps, 32);
    l = l * corr + ps;

#pragma unroll
    for (int r = 0; r < 4; ++r) {
      const float cr = __shfl(corr, g * 4 + r);
#pragma unroll
      for (int df = 0; df < 4; ++df) ao[df][r] *= cr;
    }

    bf16* plw = &Pl[w][0];
#pragma unroll
    for (int kf = 0; kf < 4; ++kf) {
      uint2 pw;
      pw.x = ((uint32_t)f2bf_bits(p[kf][1]) << 16) | (uint32_t)f2bf_bits(p[kf][0]);
      pw.y = ((uint32_t)f2bf_bits(p[kf][3]) << 16) | (uint32_t)f2bf_bits(p[kf][2]);
      *(uint2*)&plw[lr * 72 + kf * 16 + g * 4] = pw;
    }

    __builtin_amdgcn_s_setprio(1);
#pragma unroll
    for (int ks = 0; ks < 2; ++ks) {
      const short8 pa = *(const short8*)&plw[lr * 72 + ks * 32 + g * 8];
#pragma unroll
      for (int df = 0; df < 4; ++df) {
        const int row = df * 16 + lr;
        const short8 vfrag = *(const short8*)&Vts[row * 64 + ((ks * 4 + g) ^ (row & 7)) * 8];
        ao[df] = __builtin_amdgcn_mfma_f32_16x16x32_bf16(pa, vfrag, ao[df], 0, 0, 0);
      }
    }
    __builtin_amdgcn_s_setprio(0);
    __syncthreads();
  }

  const float rl = 1.0f / l;
#pragma unroll
  for (int r = 0; r < 4; ++r) {
    const float rr = __shfl(rl, g * 4 + r);
    const int qg = qb * 64 + w * 16 + g * 4 + r;
    if (qg < 257) {
      bf16* op = O + ((long)b * 257 + qg) * 768 + h * 64;
#pragma unroll
      for (int df = 0; df < 4; ++df)
        op[df * 16 + lr] = __float2bfloat16(ao[df][r] * rr);
    }
  }
}

// ---------------------------------------------------------------- launch

extern "C" void kernel_launch(void* const* d_in, const int* in_sizes, int n_in,
                              void* d_out, int out_size, void* d_ws, size_t ws_size,
                              hipStream_t stream) {
  (void)in_sizes; (void)n_in; (void)out_size;
  const float* x      = (const float*)d_in[0];
  const float* geo    = (const float*)d_in[3];
  const float* extra  = (const float*)d_in[4];
  const float* conv_w = (const float*)d_in[5];
  const float* conv_b = (const float*)d_in[6];
  const float* pe_g   = (const float*)d_in[7];
  const float* pe_b   = (const float*)d_in[8];
  const float* n1_g   = (const float*)d_in[9];
  const float* n1_b   = (const float*)d_in[10];
  const float* qkv_w  = (const float*)d_in[11];
  const float* rpb    = (const float*)d_in[12];
  const float* proj_w = (const float*)d_in[13];
  const float* proj_b = (const float*)d_in[14];
  const float* n2_g   = (const float*)d_in[15];
  const float* n2_b   = (const float*)d_in[16];
  const float* fc1_w  = (const float*)d_in[17];
  const float* fc1_b  = (const float*)d_in[18];
  const float* fc2_w  = (const float*)d_in[19];
  const float* fc2_b  = (const float*)d_in[20];
  float* out = (float*)d_out;

  // workspace layout (M padded to 16512 = 129 x 128)
  constexpr size_t SZ_WCONV = 768UL * 3456 * 2;
  constexpr size_t SZ_WQKV  = 2304UL * 768 * 2;
  constexpr size_t SZ_WPROJ = 768UL * 768 * 2;
  constexpr size_t SZ_WFC1  = 3072UL * 768 * 2;
  constexpr size_t SZ_WFC2  = 768UL * 3072 * 2;
  constexpr size_t SZ_H     = 16512UL * 768 * 2;
  constexpr size_t SZ_A     = 16384UL * 3456 * 2;
  constexpr size_t SZ_B     = 16512UL * 768 * 2;
  constexpr size_t TOTAL = SZ_WCONV + SZ_WQKV + SZ_WPROJ + SZ_WFC1 + SZ_WFC2 + SZ_H + SZ_A + SZ_B;
  if (ws_size < TOTAL) return;

  char* ws = (char*)d_ws;
  bf16* Wconv = (bf16*)ws;                    ws += SZ_WCONV;
  bf16* Wqkv  = (bf16*)ws;                    ws += SZ_WQKV;
  bf16* Wproj = (bf16*)ws;                    ws += SZ_WPROJ;
  bf16* Wfc1  = (bf16*)ws;                    ws += SZ_WFC1;
  bf16* Wfc2  = (bf16*)ws;                    ws += SZ_WFC2;
  bf16* Hb    = (bf16*)ws;                    ws += SZ_H;
  char* regA  = ws;                           ws += SZ_A;
  char* regB  = ws;
  bf16* XP   = (bf16*)regA;     // phase: conv — NHWC halo-padded input (56.8 MB)
  bf16* QKV  = (bf16*)regA;     // phase: attention
  bf16* MLPH = (bf16*)regA;     // phase: mlp
  constexpr size_t SZ_QKV = 16512UL * 2304 * 2;       // 76.1 MB
  bf16* Vt   = (bf16*)(regA + SZ_QKV);                // 31.5 MB (fits SZ_A slack)
  bf16* CO   = (bf16*)regB;     // conv out (bf16, +bias)
  bf16* Oat  = (bf16*)regB;     // attention out
  float* rpbTp = (float*)Hb;    // 46KB, Hb is free during attention

  // 1) weight casts (fused) + NHWC transpose (halo-only zero)
  convw_reorder<<<10368, 256, 0, stream>>>(conv_w, Wconv);
  cast4_kernel<<<2048, 256, 0, stream>>>(qkv_w, Wqkv, proj_w, Wproj, fc1_w, Wfc1, fc2_w, Wfc2);
  halo_zero<<<64, 256, 0, stream>>>(XP);
  nhwc_kernel<<<2048, 256, 0, stream>>>(x, XP);
  // 2) implicit conv GEMM (+bias) -> CO
  conv_gemm<<<128 * 6, 256, 0, stream>>>(XP, Wconv, conv_b, CO);
  // 3) fused embed + LN1 -> y (d_out) and Hb
  embed_ln_kernel<<<16512, 256, 0, stream>>>(CO, extra, geo, pe_g, pe_b, n1_g, n1_b, out, Hb);
  // 4) QKV GEMM
  gemm_bt<0><<<129 * 18, 256, 0, stream>>>(Hb, Wqkv, nullptr, nullptr, QKV, 2304, 768, 16448, 18);
  // 5) attention prep: rpb transpose, V transpose, zero Oat pad rows
  rpbT_kernel<<<46, 256, 0, stream>>>(rpb, rpbTp);
  vtrans_kernel<<<768, 256, 0, stream>>>(QKV, Vt);
  zero_b<<<192, 256, 0, stream>>>(Oat + 16448L * 768, 49152);
  // 6) MFMA flash attention -> Oat
  attn_mfma<<<3840, 256, 0, stream>>>(QKV, Vt, rpbTp, Oat);
  // 7) proj GEMM + bias + residual (in-place on d_out)
  gemm_bt<3><<<129 * 6, 256, 0, stream>>>(Oat, Wproj, proj_b, out, nullptr, 768, 768, 16448, 6);
  // 8) LN2 -> Hb ; FC1 (+bias+GELU) -> MLPH ; FC2 + bias + residual
  ln_kernel<<<16512, 256, 0, stream>>>(out, n2_g, n2_b, Hb, 16448);
  gemm_bt<2><<<129 * 24, 256, 0, stream>>>(Hb, Wfc1, fc1_b, nullptr, MLPH, 3072, 768, 16448, 24);
  gemm_bt<3><<<129 * 6, 256, 0, stream>>>(MLPH, Wfc2, fc2_b, out, nullptr, 768, 3072, 16448, 6);
}

// Round 18
// 606.818 us; speedup vs baseline: 1.0152x; 1.0003x over previous
//
#include <hip/hip_runtime.h>
#include <hip/hip_bf16.h>
#include <cstdint>

using bf16 = __hip_bfloat16;
typedef __attribute__((ext_vector_type(8))) short short8;
typedef __attribute__((ext_vector_type(4))) float f32x4;

// ---------------------------------------------------------------- utilities

__device__ __forceinline__ void gld_lds16(const bf16* g, bf16* l) {
  __builtin_amdgcn_global_load_lds(
      (const __attribute__((address_space(1))) void*)g,
      (__attribute__((address_space(3))) void*)l, 16, 0, 0);
}

__device__ __forceinline__ unsigned short f2bf_bits(float f) {
  uint32_t u = __builtin_bit_cast(uint32_t, f);
  uint32_t r = (u + 0x7fffu + ((u >> 16) & 1u)) >> 16;
  return (unsigned short)r;
}

// Bijective XCD-aware swizzle (m204).
__device__ __forceinline__ int xcd_swz(int bid, int nwg) {
  const int q = nwg >> 3, r = nwg & 7;
  const int x = bid & 7, o = bid >> 3;
  return (x < r ? x * (q + 1) : r * (q + 1) + (x - r) * q) + o;
}

// fused cast of the 4 plain [N,K] weights (qkv, proj, fc1, fc2) -> bf16
__global__ void cast4_kernel(const float* __restrict__ s0, bf16* __restrict__ d0,
                             const float* __restrict__ s1, bf16* __restrict__ d1,
                             const float* __restrict__ s2, bf16* __restrict__ d2,
                             const float* __restrict__ s3, bf16* __restrict__ d3)
{
  int i = blockIdx.x * blockDim.x + threadIdx.x;
  const int st = gridDim.x * blockDim.x;
  for (; i < 7077888; i += st) {
    if (i < 1769472)      d0[i] = __float2bfloat16(s0[i]);
    else if (i < 2359296) d1[i - 1769472] = __float2bfloat16(s1[i - 1769472]);
    else if (i < 4718592) d2[i - 2359296] = __float2bfloat16(s2[i - 2359296]);
    else                  d3[i - 4718592] = __float2bfloat16(s3[i - 4718592]);
  }
}

__global__ void zero_b(bf16* __restrict__ p, int n) {
  int i = blockIdx.x * blockDim.x + threadIdx.x;
  if (i < n) p[i] = __float2bfloat16(0.f);
}

// zero only the halo of xp [64,34,34,384]
__global__ __launch_bounds__(256)
void halo_zero(bf16* __restrict__ xp) {
  const int b = blockIdx.x;
  bf16* base = xp + (long)b * 34 * 34 * 384;
  const bf16 z = __float2bfloat16(0.f);
  for (int e = threadIdx.x; e < 132 * 384; e += 256) {
    const int p = e / 384, c = e % 384;
    int iy, ix;
    if (p < 34)       { iy = 0;          ix = p; }
    else if (p < 68)  { iy = 33;         ix = p - 34; }
    else if (p < 100) { iy = p - 68 + 1; ix = 0; }
    else              { iy = p - 100 + 1; ix = 33; }
    base[(iy * 34 + ix) * 384 + c] = z;
  }
}

// conv_w [D, C, 3, 3] -> [D, 3*3, C]  (k' = (ky*3+kx)*384 + c), bf16
__global__ void convw_reorder(const float* __restrict__ w, bf16* __restrict__ o) {
  int i = blockIdx.x * blockDim.x + threadIdx.x;
  if (i >= 768 * 3456) return;
  int n = i / 3456, r = i % 3456;
  int tap = r / 384, c = r % 384;
  o[i] = __float2bfloat16(w[(long)n * 3456 + c * 9 + tap]);
}

// x [64,384,32,32] f32 -> xp [64,34,34,384] bf16 (interior only; halo pre-zeroed)
__global__ __launch_bounds__(256, 4)
void nhwc_kernel(const float* __restrict__ x, bf16* __restrict__ xp) {
  __shared__ bf16 T[384 * 33];            // [c][ix+pad]
  const int biy = blockIdx.x;             // b*32 + iy
  const int b = biy >> 5, iy = biy & 31;
  const int tid = threadIdx.x;
  const int ix = tid & 31, cp = tid >> 5; // cp 0..7
  const long xrow = (long)b * 384 * 1024 + iy * 32 + ix;
#pragma unroll
  for (int t = 0; t < 48; ++t) {
    const int c = t * 8 + cp;
    T[c * 33 + ix] = __float2bfloat16(x[xrow + (long)c * 1024]);
  }
  __syncthreads();
  bf16* dst = xp + (((long)b * 34 + iy + 1) * 34 + 1) * 384;
  for (int e4 = tid; e4 < 3072; e4 += 256) {
    const int e = e4 * 4;
    const int ixr = e / 384, c = e % 384;
    ushort4 v;
    v.x = ((const unsigned short*)T)[(c + 0) * 33 + ixr];
    v.y = ((const unsigned short*)T)[(c + 1) * 33 + ixr];
    v.z = ((const unsigned short*)T)[(c + 2) * 33 + ixr];
    v.w = ((const unsigned short*)T)[(c + 3) * 33 + ixr];
    *(ushort4*)(dst + e) = v;
  }
}

// ---------------------------------------------------------------- GEMM (round-12 + T5)
// 128x128 tile, BK=64, 4 waves 2x2, SINGLE-buffered 32 KB LDS, T2 XOR swizzle
// via pre-swizzled source, hoisted LDS read pointers, XCD swizzle. 256
// threads/block REQUIRED. r18: s_setprio(1) around the 32-MFMA cluster —
// 5 co-resident blocks/CU at staggered K-steps give the scheduler the same
// phase-diversity that made setprio pay on attention (r17: +8 us).
// EPI: 0 bf16 out; 1 +bias; 2 +bias+GELU; 3 fp32 residual RMW (row<Mreal).
template <int EPI>
__global__ __launch_bounds__(256, 2)
void gemm_bt(const bf16* __restrict__ A, const bf16* __restrict__ Bw,
             const float* __restrict__ bias, float* __restrict__ outf,
             bf16* __restrict__ outb, int N, int K, int Mreal, int ntn)
{
  __shared__ bf16 As[128 * 64];
  __shared__ bf16 Bs[128 * 64];
  const int bid = xcd_swz(blockIdx.x, gridDim.x);
  const int mt = bid / ntn, nt = bid % ntn;
  const int tid = threadIdx.x;
  const int lane = tid & 63, wave = tid >> 6;
  const int wm = wave >> 1, wn = wave & 1;
  const int lr = lane & 15, lg = lane >> 4;

  f32x4 acc[4][4];
#pragma unroll
  for (int i = 0; i < 4; ++i)
#pragma unroll
    for (int j = 0; j < 4; ++j) acc[i][j] = (f32x4){0.f, 0.f, 0.f, 0.f};

  const int arow = tid >> 3;                               // 0..31
  const int scol = (((tid & 7) ^ (arow & 7))) * 8;         // pre-swizzled source col
  const bf16* ag = A + ((long)mt * 128 + arow) * K + scol;
  const bf16* bg = Bw + ((long)nt * 128 + arow) * K + scol;

  const int xs0 = ((lg)     ^ (lr & 7)) * 16;              // ks=0 K-chunk byte off
  const int xs1 = ((lg + 4) ^ (lr & 7)) * 16;              // ks=1
  const char* pa0 = (const char*)(&As[0]) + (wm * 64 + lr) * 128 + xs0;
  const char* pa1 = (const char*)(&As[0]) + (wm * 64 + lr) * 128 + xs1;
  const char* pb0 = (const char*)(&Bs[0]) + (wn * 64 + lr) * 128 + xs0;
  const char* pb1 = (const char*)(&Bs[0]) + (wn * 64 + lr) * 128 + xs1;

  const int nk = K >> 6;
  for (int t = 0; t < nk; ++t) {
    const int k0 = t << 6;
#pragma unroll
    for (int j = 0; j < 4; ++j) {
      gld_lds16(ag + (long)(j * 32) * K + k0, &As[(j * 256 + tid) * 8]);
      gld_lds16(bg + (long)(j * 32) * K + k0, &Bs[(j * 256 + tid) * 8]);
    }
    __syncthreads();
    __builtin_amdgcn_s_setprio(1);
#pragma unroll
    for (int ks = 0; ks < 2; ++ks) {
      const char* pa = ks ? pa1 : pa0;
      const char* pb = ks ? pb1 : pb0;
      short8 af[4], bv[4];
#pragma unroll
      for (int i = 0; i < 4; ++i) af[i] = *(const short8*)(pa + i * 2048);
#pragma unroll
      for (int i = 0; i < 4; ++i) bv[i] = *(const short8*)(pb + i * 2048);
#pragma unroll
      for (int i = 0; i < 4; ++i)
#pragma unroll
        for (int j = 0; j < 4; ++j)
          acc[i][j] = __builtin_amdgcn_mfma_f32_16x16x32_bf16(af[i], bv[j], acc[i][j], 0, 0, 0);
    }
    __builtin_amdgcn_s_setprio(0);
    __syncthreads();
  }

  const int rbase = mt * 128 + wm * 64 + (lane >> 4) * 4;
  const int cbase = nt * 128 + wn * 64 + lr;
#pragma unroll
  for (int i = 0; i < 4; ++i) {
#pragma unroll
    for (int j = 0; j < 4; ++j) {
      const int col = cbase + j * 16;
      float bvv = 0.f;
      if constexpr (EPI != 0) bvv = bias[col];
#pragma unroll
      for (int r = 0; r < 4; ++r) {
        const int row = rbase + i * 16 + r;
        const float v = acc[i][j][r];
        if constexpr (EPI == 0) {
          outb[(long)row * N + col] = __float2bfloat16(v);
        } else if constexpr (EPI == 1) {
          outb[(long)row * N + col] = __float2bfloat16(v + bvv);
        } else if constexpr (EPI == 2) {
          const float t = v + bvv;
          outb[(long)row * N + col] =
              __float2bfloat16(0.5f * t * (1.0f + erff(t * 0.70710678118f)));
        } else {
          if (row < Mreal) {
            const long o = (long)row * N + col;
            outf[o] = outf[o] + v + bvv;
          }
        }
      }
    }
  }
}

// ---------------------------------------------------------------- implicit conv GEMM (round-12 + T5)
__global__ __launch_bounds__(256, 2)
void conv_gemm(const bf16* __restrict__ xp, const bf16* __restrict__ Bw,
               const float* __restrict__ bias, bf16* __restrict__ outb)
{
  __shared__ bf16 As[128 * 64];
  __shared__ bf16 Bs[128 * 64];
  const int bid = xcd_swz(blockIdx.x, gridDim.x);
  const int mt = bid / 6, nt = bid % 6;
  const int tid = threadIdx.x;
  const int lane = tid & 63, wave = tid >> 6;
  const int wm = wave >> 1, wn = wave & 1;
  const int lr = lane & 15, lg = lane >> 4;

  f32x4 acc[4][4];
#pragma unroll
  for (int i = 0; i < 4; ++i)
#pragma unroll
    for (int j = 0; j < 4; ++j) acc[i][j] = (f32x4){0.f, 0.f, 0.f, 0.f};

  const int arow = tid >> 3;
  const int scol = (((tid & 7) ^ (arow & 7))) * 8;
  long abase[4];
#pragma unroll
  for (int j = 0; j < 4; ++j) {
    const int m = mt * 128 + j * 32 + arow;
    const int b = m >> 8, p = m & 255;
    const int gy = p >> 4, gx = p & 15;
    abase[j] = (((long)b * 34 + 2 * gy) * 34 + 2 * gx) * 384 + scol;
  }
  const bf16* bg = Bw + ((long)nt * 128 + arow) * 3456 + scol;

  const int xs0 = ((lg)     ^ (lr & 7)) * 16;
  const int xs1 = ((lg + 4) ^ (lr & 7)) * 16;
  const char* pa0 = (const char*)(&As[0]) + (wm * 64 + lr) * 128 + xs0;
  const char* pa1 = (const char*)(&As[0]) + (wm * 64 + lr) * 128 + xs1;
  const char* pb0 = (const char*)(&Bs[0]) + (wn * 64 + lr) * 128 + xs0;
  const char* pb1 = (const char*)(&Bs[0]) + (wn * 64 + lr) * 128 + xs1;

  for (int t = 0; t < 54; ++t) {
    const int tap = t / 6, kc = (t % 6) * 64;
    const int toff = ((tap / 3) * 34 + (tap % 3)) * 384 + kc;
#pragma unroll
    for (int j = 0; j < 4; ++j) {
      gld_lds16(xp + abase[j] + toff, &As[(j * 256 + tid) * 8]);
      gld_lds16(bg + (long)(j * 32) * 3456 + t * 64, &Bs[(j * 256 + tid) * 8]);
    }
    __syncthreads();
    __builtin_amdgcn_s_setprio(1);
#pragma unroll
    for (int ks = 0; ks < 2; ++ks) {
      const char* pa = ks ? pa1 : pa0;
      const char* pb = ks ? pb1 : pb0;
      short8 af[4], bv[4];
#pragma unroll
      for (int i = 0; i < 4; ++i) af[i] = *(const short8*)(pa + i * 2048);
#pragma unroll
      for (int i = 0; i < 4; ++i) bv[i] = *(const short8*)(pb + i * 2048);
#pragma unroll
      for (int i = 0; i < 4; ++i)
#pragma unroll
        for (int j = 0; j < 4; ++j)
          acc[i][j] = __builtin_amdgcn_mfma_f32_16x16x32_bf16(af[i], bv[j], acc[i][j], 0, 0, 0);
    }
    __builtin_amdgcn_s_setprio(0);
    __syncthreads();
  }

  const int rbase = mt * 128 + wm * 64 + (lane >> 4) * 4;
  const int cbase = nt * 128 + wn * 64 + lr;
#pragma unroll
  for (int i = 0; i < 4; ++i) {
#pragma unroll
    for (int j = 0; j < 4; ++j) {
      const int col = cbase + j * 16;
      const float bvv = bias[col];
#pragma unroll
      for (int r = 0; r < 4; ++r) {
        const int row = rbase + i * 16 + r;
        outb[(long)row * 768 + col] = __float2bfloat16(acc[i][j][r] + bvv);
      }
    }
  }
}

// ---------------------------------------------------------------- fused embed + LN1
__global__ __launch_bounds__(256, 4)
void embed_ln_kernel(const bf16* __restrict__ CO, const float* __restrict__ extra,
                     const float* __restrict__ geo, const float* __restrict__ pe_g,
                     const float* __restrict__ pe_b, const float* __restrict__ n1_g,
                     const float* __restrict__ n1_b, float* __restrict__ y,
                     bf16* __restrict__ H)
{
  const int row = blockIdx.x;
  const int tid = threadIdx.x;
  __shared__ float red[2][4];
  const int wave = tid >> 6, lane = tid & 63;
  if (row >= 16448) {
#pragma unroll
    for (int u = 0; u < 3; ++u) H[(long)row * 768 + tid + u * 256] = __float2bfloat16(0.f);
    return;
  }
  const int b = row / 257, t = row % 257;
  float yv[3];
  if (t == 0) {
#pragma unroll
    for (int u = 0; u < 3; ++u) {
      const int d = tid + u * 256;
      yv[u] = extra[d] + geo[d];
    }
  } else {
    const bf16* src = CO + (long)(b * 256 + (t - 1)) * 768;
    float v[3]; float s = 0.f, s2 = 0.f;
#pragma unroll
    for (int u = 0; u < 3; ++u) {
      v[u] = __bfloat162float(src[tid + u * 256]);
      s += v[u]; s2 += v[u] * v[u];
    }
#pragma unroll
    for (int off = 32; off > 0; off >>= 1) { s += __shfl_xor(s, off); s2 += __shfl_xor(s2, off); }
    if (lane == 0) { red[0][wave] = s; red[1][wave] = s2; }
    __syncthreads();
    const float S = red[0][0] + red[0][1] + red[0][2] + red[0][3];
    const float S2 = red[1][0] + red[1][1] + red[1][2] + red[1][3];
    const float mean = S * (1.f / 768.f);
    const float var = S2 * (1.f / 768.f) - mean * mean;
    const float rinv = rsqrtf(var + 1e-5f);
    __syncthreads();   // red[] reused below
#pragma unroll
    for (int u = 0; u < 3; ++u) {
      const int d = tid + u * 256;
      yv[u] = (v[u] - mean) * rinv * pe_g[d] + pe_b[d] + geo[(long)t * 768 + d];
    }
  }
#pragma unroll
  for (int u = 0; u < 3; ++u) y[(long)row * 768 + tid + u * 256] = yv[u];
  float s = 0.f, s2 = 0.f;
#pragma unroll
  for (int u = 0; u < 3; ++u) { s += yv[u]; s2 += yv[u] * yv[u]; }
#pragma unroll
  for (int off = 32; off > 0; off >>= 1) { s += __shfl_xor(s, off); s2 += __shfl_xor(s2, off); }
  if (lane == 0) { red[0][wave] = s; red[1][wave] = s2; }
  __syncthreads();
  const float S = red[0][0] + red[0][1] + red[0][2] + red[0][3];
  const float S2 = red[1][0] + red[1][1] + red[1][2] + red[1][3];
  const float mean = S * (1.f / 768.f);
  const float var = S2 * (1.f / 768.f) - mean * mean;
  const float rinv = rsqrtf(var + 1e-5f);
#pragma unroll
  for (int u = 0; u < 3; ++u) {
    const int d = tid + u * 256;
    H[(long)row * 768 + d] = __float2bfloat16((yv[u] - mean) * rinv * n1_g[d] + n1_b[d]);
  }
}

// ---------------------------------------------------------------- LN -> bf16 (pad rows zeroed)
__global__ __launch_bounds__(256, 4)
void ln_kernel(const float* __restrict__ y, const float* __restrict__ g,
               const float* __restrict__ bta, bf16* __restrict__ H, int Mreal)
{
  const int row = blockIdx.x;
  const int tid = threadIdx.x;
  if (row >= Mreal) {
#pragma unroll
    for (int u = 0; u < 3; ++u) H[(long)row * 768 + tid + u * 256] = __float2bfloat16(0.f);
    return;
  }
  const float* src = y + (long)row * 768;
  float v[3]; float s = 0.f, s2 = 0.f;
#pragma unroll
  for (int u = 0; u < 3; ++u) { v[u] = src[tid + u * 256]; s += v[u]; s2 += v[u] * v[u]; }
#pragma unroll
  for (int off = 32; off > 0; off >>= 1) { s += __shfl_xor(s, off); s2 += __shfl_xor(s2, off); }
  __shared__ float red[2][4];
  const int wave = tid >> 6, lane = tid & 63;
  if (lane == 0) { red[0][wave] = s; red[1][wave] = s2; }
  __syncthreads();
  const float S = red[0][0] + red[0][1] + red[0][2] + red[0][3];
  const float S2 = red[1][0] + red[1][1] + red[1][2] + red[1][3];
  const float mean = S * (1.f / 768.f);
  const float var = S2 * (1.f / 768.f) - mean * mean;
  const float rinv = rsqrtf(var + 1e-5f);
#pragma unroll
  for (int u = 0; u < 3; ++u) {
    const int d = tid + u * 256;
    H[(long)row * 768 + d] = __float2bfloat16((v[u] - mean) * rinv * g[d] + bta[d]);
  }
}

// ---------------------------------------------------------------- rpb transpose: [961,12] -> [12,961]
__global__ void rpbT_kernel(const float* __restrict__ rpb, float* __restrict__ rpbT) {
  int i = blockIdx.x * blockDim.x + threadIdx.x;
  if (i >= 12 * 961) return;
  int h = i / 961, t = i % 961;
  rpbT[i] = rpb[t * 12 + h];
}

// ---------------------------------------------------------------- V transpose:
// QKV V-part [token][d] -> Vt[b][h][d][320] (keys padded with zeros)
__global__ __launch_bounds__(256, 2)
void vtrans_kernel(const bf16* __restrict__ qkv, bf16* __restrict__ vt) {
  __shared__ bf16 Vl[257 * 65];
  const int bh = blockIdx.x;  // b*12+h
  const int b = bh / 12, h = bh % 12;
  const long src = (long)b * 257 * 2304 + 1536 + h * 64;
  for (int e = threadIdx.x; e < 257 * 64; e += 256) {
    const int t = e >> 6, d = e & 63;
    Vl[t * 65 + d] = qkv[src + (long)t * 2304 + d];
  }
  __syncthreads();
  const bf16 z = __float2bfloat16(0.f);
  const long dst = (long)bh * 64 * 320;
  for (int e = threadIdx.x; e < 64 * 320; e += 256) {
    const int d = e / 320, tp = e % 320;
    vt[dst + e] = (tp < 257) ? Vl[tp * 65 + d] : z;
  }
}

// ---------------------------------------------------------------- MFMA flash attention (r17 T5 kept)
__global__ __launch_bounds__(256, 2)
void attn_mfma(const bf16* __restrict__ qkv, const bf16* __restrict__ vt,
               const float* __restrict__ rpbT, bf16* __restrict__ O)
{
  __shared__ bf16 Ks[64 * 64];
  __shared__ bf16 Vts[64 * 64];
  __shared__ float rpb_s[961];
  __shared__ bf16 Pl[4][16 * 72];

  const int bid = blockIdx.x;
  const int qb = bid % 5;
  const int bh = bid / 5;
  const int h = bh % 12, b = bh / 12;
  const int tid = threadIdx.x;
  const int lane = tid & 63, w = tid >> 6;
  const int lr = lane & 15, g = lane >> 4;

  for (int t = tid; t < 961; t += 256) rpb_s[t] = rpbT[h * 961 + t];

  const long qkv_bh = (long)b * 257 * 2304 + h * 64;
  const long vt_bh = (long)bh * 64 * 320;

  const int q_tok = qb * 64 + w * 16 + lr;
  const bf16* qp = qkv + qkv_bh + (long)q_tok * 2304;
  short8 qf[2];
  qf[0] = *(const short8*)(qp + g * 8);
  qf[1] = *(const short8*)(qp + 32 + g * 8);

  f32x4 ao[4];
#pragma unroll
  for (int df = 0; df < 4; ++df) ao[df] = (f32x4){0.f, 0.f, 0.f, 0.f};
  float mval = -1e30f, l = 0.f;

  for (int ck = 0; ck < 5; ++ck) {
    const int c0 = ck * 64;
#pragma unroll
    for (int it = 0; it < 2; ++it) {
      const int beta = it * 256 + tid;
      const int row = beta >> 3, cb = beta & 7;
      const int cbs = cb ^ (row & 7);
      gld_lds16(qkv + qkv_bh + (long)(c0 + row) * 2304 + 768 + cbs * 8, &Ks[beta * 8]);
      gld_lds16(vt + vt_bh + (long)row * 320 + c0 + cbs * 8, &Vts[beta * 8]);
    }
    __syncthreads();

    f32x4 st[4];
#pragma unroll
    for (int kf = 0; kf < 4; ++kf) st[kf] = (f32x4){0.f, 0.f, 0.f, 0.f};
    __builtin_amdgcn_s_setprio(1);
#pragma unroll
    for (int ks = 0; ks < 2; ++ks) {
#pragma unroll
      for (int kf = 0; kf < 4; ++kf) {
        const int row = kf * 16 + lr;
        const short8 kfrag = *(const short8*)&Ks[row * 64 + ((ks * 4 + g) ^ (row & 7)) * 8];
        st[kf] = __builtin_amdgcn_mfma_f32_16x16x32_bf16(kfrag, qf[ks], st[kf], 0, 0, 0);
      }
    }
    __builtin_amdgcn_s_setprio(0);

    float p[4][4];
    float t = -1e30f;
#pragma unroll
    for (int kf = 0; kf < 4; ++kf) {
#pragma unroll
      for (int r = 0; r < 4; ++r) {
        const int key = c0 + kf * 16 + g * 4 + r;
        float s;
        if (key < 257) {
          int idx = 0;
          if (q_tok > 0 && key > 0) {
            const int qi = q_tok - 1, kj = key - 1;
            idx = ((qi >> 4) - (kj >> 4) + 15) * 31 + ((qi & 15) - (kj & 15) + 15);
            idx = idx < 0 ? 0 : (idx > 960 ? 960 : idx);
          }
          s = 0.125f * st[kf][r] + rpb_s[idx];
        } else {
          s = -1e30f;
        }
        p[kf][r] = s;
        t = fmaxf(t, s);
      }
    }
    t = fmaxf(t, __shfl_xor(t, 16));
    t = fmaxf(t, __shfl_xor(t, 32));
    const float mnew = fmaxf(mval, t);
    const float corr = __expf(mval - mnew);
    mval = mnew;
    float ps = 0.f;
#pragma unroll
    for (int kf = 0; kf < 4; ++kf)
#pragma unroll
      for (int r = 0; r < 4; ++r) { p[kf][r] = __expf(p[kf][r] - mnew); ps += p[kf][r]; }
    ps += __shfl_xor(ps, 16);
    ps += __shfl_xor(ps, 32);
    l = l * corr + ps;

#pragma unroll
    for (int r = 0; r < 4; ++r) {
      const float cr = __shfl(corr, g * 4 + r);
#pragma unroll
      for (int df = 0; df < 4; ++df) ao[df][r] *= cr;
    }

    bf16* plw = &Pl[w][0];
#pragma unroll
    for (int kf = 0; kf < 4; ++kf) {
      uint2 pw;
      pw.x = ((uint32_t)f2bf_bits(p[kf][1]) << 16) | (uint32_t)f2bf_bits(p[kf][0]);
      pw.y = ((uint32_t)f2bf_bits(p[kf][3]) << 16) | (uint32_t)f2bf_bits(p[kf][2]);
      *(uint2*)&plw[lr * 72 + kf * 16 + g * 4] = pw;
    }

    __builtin_amdgcn_s_setprio(1);
#pragma unroll
    for (int ks = 0; ks < 2; ++ks) {
      const short8 pa = *(const short8*)&plw[lr * 72 + ks * 32 + g * 8];
#pragma unroll
      for (int df = 0; df < 4; ++df) {
        const int row = df * 16 + lr;
        const short8 vfrag = *(const short8*)&Vts[row * 64 + ((ks * 4 + g) ^ (row & 7)) * 8];
        ao[df] = __builtin_amdgcn_mfma_f32_16x16x32_bf16(pa, vfrag, ao[df], 0, 0, 0);
      }
    }
    __builtin_amdgcn_s_setprio(0);
    __syncthreads();
  }

  const float rl = 1.0f / l;
#pragma unroll
  for (int r = 0; r < 4; ++r) {
    const float rr = __shfl(rl, g * 4 + r);
    const int qg = qb * 64 + w * 16 + g * 4 + r;
    if (qg < 257) {
      bf16* op = O + ((long)b * 257 + qg) * 768 + h * 64;
#pragma unroll
      for (int df = 0; df < 4; ++df)
        op[df * 16 + lr] = __float2bfloat16(ao[df][r] * rr);
    }
  }
}

// ---------------------------------------------------------------- launch

extern "C" void kernel_launch(void* const* d_in, const int* in_sizes, int n_in,
                              void* d_out, int out_size, void* d_ws, size_t ws_size,
                              hipStream_t stream) {
  (void)in_sizes; (void)n_in; (void)out_size;
  const float* x      = (const float*)d_in[0];
  const float* geo    = (const float*)d_in[3];
  const float* extra  = (const float*)d_in[4];
  const float* conv_w = (const float*)d_in[5];
  const float* conv_b = (const float*)d_in[6];
  const float* pe_g   = (const float*)d_in[7];
  const float* pe_b   = (const float*)d_in[8];
  const float* n1_g   = (const float*)d_in[9];
  const float* n1_b   = (const float*)d_in[10];
  const float* qkv_w  = (const float*)d_in[11];
  const float* rpb    = (const float*)d_in[12];
  const float* proj_w = (const float*)d_in[13];
  const float* proj_b = (const float*)d_in[14];
  const float* n2_g   = (const float*)d_in[15];
  const float* n2_b   = (const float*)d_in[16];
  const float* fc1_w  = (const float*)d_in[17];
  const float* fc1_b  = (const float*)d_in[18];
  const float* fc2_w  = (const float*)d_in[19];
  const float* fc2_b  = (const float*)d_in[20];
  float* out = (float*)d_out;

  // workspace layout (M padded to 16512 = 129 x 128)
  constexpr size_t SZ_WCONV = 768UL * 3456 * 2;
  constexpr size_t SZ_WQKV  = 2304UL * 768 * 2;
  constexpr size_t SZ_WPROJ = 768UL * 768 * 2;
  constexpr size_t SZ_WFC1  = 3072UL * 768 * 2;
  constexpr size_t SZ_WFC2  = 768UL * 3072 * 2;
  constexpr size_t SZ_H     = 16512UL * 768 * 2;
  constexpr size_t SZ_A     = 16384UL * 3456 * 2;
  constexpr size_t SZ_B     = 16512UL * 768 * 2;
  constexpr size_t TOTAL = SZ_WCONV + SZ_WQKV + SZ_WPROJ + SZ_WFC1 + SZ_WFC2 + SZ_H + SZ_A + SZ_B;
  if (ws_size < TOTAL) return;

  char* ws = (char*)d_ws;
  bf16* Wconv = (bf16*)ws;                    ws += SZ_WCONV;
  bf16* Wqkv  = (bf16*)ws;                    ws += SZ_WQKV;
  bf16* Wproj = (bf16*)ws;                    ws += SZ_WPROJ;
  bf16* Wfc1  = (bf16*)ws;                    ws += SZ_WFC1;
  bf16* Wfc2  = (bf16*)ws;                    ws += SZ_WFC2;
  bf16* Hb    = (bf16*)ws;                    ws += SZ_H;
  char* regA  = ws;                           ws += SZ_A;
  char* regB  = ws;
  bf16* XP   = (bf16*)regA;     // phase: conv — NHWC halo-padded input (56.8 MB)
  bf16* QKV  = (bf16*)regA;     // phase: attention
  bf16* MLPH = (bf16*)regA;     // phase: mlp
  constexpr size_t SZ_QKV = 16512UL * 2304 * 2;       // 76.1 MB
  bf16* Vt   = (bf16*)(regA + SZ_QKV);                // 31.5 MB (fits SZ_A slack)
  bf16* CO   = (bf16*)regB;     // conv out (bf16, +bias)
  bf16* Oat  = (bf16*)regB;     // attention out
  float* rpbTp = (float*)Hb;    // 46KB, Hb is free during attention

  // 1) weight casts (fused) + NHWC transpose (halo-only zero)
  convw_reorder<<<10368, 256, 0, stream>>>(conv_w, Wconv);
  cast4_kernel<<<2048, 256, 0, stream>>>(qkv_w, Wqkv, proj_w, Wproj, fc1_w, Wfc1, fc2_w, Wfc2);
  halo_zero<<<64, 256, 0, stream>>>(XP);
  nhwc_kernel<<<2048, 256, 0, stream>>>(x, XP);
  // 2) implicit conv GEMM (+bias) -> CO
  conv_gemm<<<128 * 6, 256, 0, stream>>>(XP, Wconv, conv_b, CO);
  // 3) fused embed + LN1 -> y (d_out) and Hb
  embed_ln_kernel<<<16512, 256, 0, stream>>>(CO, extra, geo, pe_g, pe_b, n1_g, n1_b, out, Hb);
  // 4) QKV GEMM
  gemm_bt<0><<<129 * 18, 256, 0, stream>>>(Hb, Wqkv, nullptr, nullptr, QKV, 2304, 768, 16448, 18);
  // 5) attention prep: rpb transpose, V transpose, zero Oat pad rows
  rpbT_kernel<<<46, 256, 0, stream>>>(rpb, rpbTp);
  vtrans_kernel<<<768, 256, 0, stream>>>(QKV, Vt);
  zero_b<<<192, 256, 0, stream>>>(Oat + 16448L * 768, 49152);
  // 6) MFMA flash attention -> Oat
  attn_mfma<<<3840, 256, 0, stream>>>(QKV, Vt, rpbTp, Oat);
  // 7) proj GEMM + bias + residual (in-place on d_out)
  gemm_bt<3><<<129 * 6, 256, 0, stream>>>(Oat, Wproj, proj_b, out, nullptr, 768, 768, 16448, 6);
  // 8) LN2 -> Hb ; FC1 (+bias+GELU) -> MLPH ; FC2 + bias + residual
  ln_kernel<<<16512, 256, 0, stream>>>(out, n2_g, n2_b, Hb, 16448);
  gemm_bt<2><<<129 * 24, 256, 0, stream>>>(Hb, Wfc1, fc1_b, nullptr, MLPH, 3072, 768, 16448, 24);
  gemm_bt<3><<<129 * 6, 256, 0, stream>>>(MLPH, Wfc2, fc2_b, out, nullptr, 768, 3072, 16448, 6);
}